// Round 6
// baseline (456.621 us; speedup 1.0000x reference)
//
#include <hip/hip_runtime.h>

// Problem constants (from reference setup_inputs / NUM_DISPARITIES)
constexpr int B = 2, C = 32, H = 136, W = 240, D = 48;
constexpr int PLANE   = H * W;         // 32640 floats per (b,c,d) plane
constexpr int PLANE4  = PLANE / 4;     // 8160 float4 per plane
constexpr int QROWS   = 34;            // rows per staged quarter (136 = 4*34)
constexpr int NQ      = H / QROWS;     // 4 quarters
constexpr int QSLOTS  = QROWS * W / 4; // 2040 float4 per quarter
constexpr int DPB     = 4;             // disparities per block (d0 = 4*k)
constexpr int NBLK    = B * C * (D / DPB);  // 768 blocks = 3.0 per CU
constexpr int LROW16  = 73;            // 16B slots per LDS row: 13 pad + 60 data
constexpr float CLAMPV = 1000.0f;

typedef float v4f __attribute__((ext_vector_type(4)));

__device__ __forceinline__ float clampv(float x) {
    return fminf(CLAMPV, fmaxf(-CLAMPV, x));
}
// exact floor(s/60) for s in [0, 2341)
__device__ __forceinline__ int div60(int s) { return (s * 2185) >> 17; }

// STREAM-LINEARITY TEST. Falsified so far: NT-vs-plain (R4), run length
// (R3), 128B-line coverage (R5) -- all pin at ~2.7 TB/s vs fill's 6.4.
// Untested regime: few long strictly-linear streams. Block = 4 consecutive
// output planes (bc, d0..d0+3): its whole 522 KB output is ONE address-
// ordered linear sweep; 768 streams chip-wide (fill-like), every store a
// full-line 128B-aligned chunk (plane stride 130560 = 1020*128, quarter
// stride 32640 = 255*128).
//
// LDS: right quarter (34 rows) staged per (J,q) phase; each row = 13 zero
// 16B-slots (52 floats, covers d<=47 left overhang -> free w<d masking) +
// 60 data slots. Window for out[row, 4*c4 + e], d = 4*d4 + J:
//   LDS float addr = 292*r + 52 + 4*c4 - d + e  = floats [4t-J .. 4t-J+3],
//   t = 73*r + 13 + c4 - d4  -> aligned slot Q=sR[t], X=sR[t-1]:
//   J=0: [Q0 Q1 Q2 Q3]  J=1: [X3 Q0 Q1 Q2]  J=2: [X2 X3 Q0 Q1]  J=3: [X1 X2 X3 Q0]
// (compile-time extraction; J == d mod 4 because d0 % 4 == 0).
template<int J>
__device__ __forceinline__ void phaseJ(v4f* __restrict__ sR,
                                       const v4f* __restrict__ lp4,
                                       const v4f* __restrict__ rp4,
                                       v4f* __restrict__ op4,   // plane d0+J base
                                       int d4, int tid) {
    for (int q = 0; q < NQ; ++q) {
        __syncthreads();   // prior phase's readers done before overwrite
        for (int i = tid; i < QSLOTS; i += 512) {
            const int r = div60(i);
            sR[r * LROW16 + 13 + (i - 60 * r)] = rp4[q * QSLOTS + i];
        }
        __syncthreads();
        #pragma unroll
        for (int it = 0; it < 4; ++it) {
            const int s = tid + 512 * it;
            if (s < QSLOTS) {
                const int r  = div60(s);
                const int c4 = s - 60 * r;
                const int t  = r * LROW16 + 13 + c4 - d4;
                const v4f l4 = lp4[q * QSLOTS + s];
                const v4f Q  = sR[t];
                v4f w;
                if constexpr (J == 0) {
                    w = Q;
                } else {
                    const v4f X = sR[t - 1];
                    if constexpr (J == 1)      { w.x=X.w; w.y=Q.x; w.z=Q.y; w.w=Q.z; }
                    else if constexpr (J == 2) { w.x=X.z; w.y=X.w; w.z=Q.x; w.w=Q.y; }
                    else                       { w.x=X.y; w.y=X.z; w.z=X.w; w.w=Q.x; }
                }
                v4f o;
                o.x = clampv(l4.x * w.x); o.y = clampv(l4.y * w.y);
                o.z = clampv(l4.z * w.z); o.w = clampv(l4.w * w.w);
                op4[q * QSLOTS + s] = o;   // plain store, full-line, linear
            }
        }
    }
}

__global__ __launch_bounds__(512) void CostVolume_4939212390829_kernel(
        const float* __restrict__ left,
        const float* __restrict__ right,
        float* __restrict__ out) {
    const int blk = blockIdx.x;
    const int bc  = blk / (D / DPB);           // 0..63
    const int d4  = blk - bc * (D / DPB);      // 0..11, d0 = 4*d4
    const int tid = threadIdx.x;

    __shared__ v4f sR[QROWS * LROW16];         // 34*73*16 = 39,712 B -> 4 blk/CU

    const v4f* __restrict__ lp4 = (const v4f*)left  + (size_t)bc * PLANE4;
    const v4f* __restrict__ rp4 = (const v4f*)right + (size_t)bc * PLANE4;
    v4f* __restrict__ op4 = (v4f*)out + ((size_t)bc * D + 4 * d4) * PLANE4;

    // zero pads once (staging never touches slots 0..12 of a row)
    if (tid < QROWS * 13) {
        const int r = tid / 13, c = tid - 13 * r;
        sR[r * LROW16 + c] = (v4f){0.f, 0.f, 0.f, 0.f};
    }
    // visibility of pads handled by the first __syncthreads() inside phaseJ

    phaseJ<0>(sR, lp4, rp4, op4,              d4, tid);
    phaseJ<1>(sR, lp4, rp4, op4 +     PLANE4, d4, tid);
    phaseJ<2>(sR, lp4, rp4, op4 + 2 * PLANE4, d4, tid);
    phaseJ<3>(sR, lp4, rp4, op4 + 3 * PLANE4, d4, tid);
}

extern "C" void kernel_launch(void* const* d_in, const int* in_sizes, int n_in,
                              void* d_out, int out_size, void* d_ws, size_t ws_size,
                              hipStream_t stream) {
    const float* left  = (const float*)d_in[0];
    const float* right = (const float*)d_in[1];
    float* out = (float*)d_out;
    (void)in_sizes; (void)n_in; (void)out_size; (void)d_ws; (void)ws_size;

    CostVolume_4939212390829_kernel<<<NBLK, 512, 0, stream>>>(left, right, out);
}